// Round 5
// baseline (476.886 us; speedup 1.0000x reference)
//
#include <hip/hip_runtime.h>
#include <stdint.h>

typedef __attribute__((ext_vector_type(4))) float f32x4;
typedef __attribute__((ext_vector_type(8))) __bf16 bf16x8;

#define DEV static __device__ __forceinline__

DEV unsigned short f2bf(float f){
    uint32_t u = __float_as_uint(f);
    u += 0x7FFFu + ((u >> 16) & 1u);   // RNE
    return (unsigned short)(u >> 16);
}
DEV uint32_t pk2bf(float a, float b){
    return (uint32_t)f2bf(a) | ((uint32_t)f2bf(b) << 16);
}

#define GLDS16(g, l) __builtin_amdgcn_global_load_lds( \
    (const __attribute__((address_space(1))) void*)(g), \
    (__attribute__((address_space(3))) void*)(l), 16, 0, 0)

// ---------------- f32 -> bf16 cast (weights) ----------------
__global__ __launch_bounds__(256) void k_cast_bf16(const float* __restrict__ in,
                                                   unsigned short* __restrict__ out, int n4){
    int i = blockIdx.x * 256 + threadIdx.x;
    if (i < n4){
        float4 v = ((const float4*)in)[i];
        ((ushort4*)out)[i] = make_ushort4(f2bf(v.x), f2bf(v.y), f2bf(v.z), f2bf(v.w));
    }
}

// ---------------- ada = c @ ada_w^T + ada_b  (2 x 6144) ----------------
__global__ __launch_bounds__(256) void k_ada(const float* __restrict__ c,
                                             const float* __restrict__ aw,
                                             const float* __restrict__ ab,
                                             float* __restrict__ out){
    int wid  = blockIdx.x * 4 + (threadIdx.x >> 6);
    int lane = threadIdx.x & 63;
    int b = wid / 6144, r = wid % 6144;
    const float4* cw = (const float4*)(c + (size_t)b * 1024);
    const float4* wr = (const float4*)(aw + (size_t)r * 1024);
    float s = 0.f;
    #pragma unroll
    for (int i = 0; i < 4; i++){
        float4 a = wr[lane + i * 64];
        float4 q = cw[lane + i * 64];
        s += a.x*q.x + a.y*q.y + a.z*q.z + a.w*q.w;
    }
    #pragma unroll
    for (int off = 32; off > 0; off >>= 1) s += __shfl_down(s, off);
    if (lane == 0) out[wid] = s + ab[r];
}

// ---------------- LN + modulate -> bf16 ----------------
__global__ __launch_bounds__(256) void k_ln_mod(const float* __restrict__ x,
                                                const float* __restrict__ w,
                                                const float* __restrict__ ada,
                                                int sh_off, int sc_off,
                                                unsigned short* __restrict__ out){
    int row = blockIdx.x;
    int b   = row >> 11;
    int tid = threadIdx.x;
    float4 v = ((const float4*)(x + (size_t)row * 1024))[tid];
    float s  = v.x + v.y + v.z + v.w;
    float ss = v.x*v.x + v.y*v.y + v.z*v.z + v.w*v.w;
    #pragma unroll
    for (int off = 32; off > 0; off >>= 1){ s += __shfl_down(s, off); ss += __shfl_down(ss, off); }
    __shared__ float red[8];
    int wv = tid >> 6;
    if ((tid & 63) == 0){ red[wv] = s; red[4 + wv] = ss; }
    __syncthreads();
    float S  = red[0] + red[1] + red[2] + red[3];
    float SS = red[4] + red[5] + red[6] + red[7];
    float mu   = S * (1.f / 1024.f);
    float rstd = rsqrtf(SS * (1.f / 1024.f) - mu * mu + 1e-5f);
    const float* adab = ada + (size_t)b * 6144;
    float4 wv4 = ((const float4*)w)[tid];
    float4 sh  = ((const float4*)(adab + sh_off))[tid];
    float4 sc  = ((const float4*)(adab + sc_off))[tid];
    float h0 = (v.x - mu) * rstd * wv4.x * (1.f + sc.x) + sh.x;
    float h1 = (v.y - mu) * rstd * wv4.y * (1.f + sc.y) + sh.y;
    float h2 = (v.z - mu) * rstd * wv4.z * (1.f + sc.z) + sh.z;
    float h3 = (v.w - mu) * rstd * wv4.w * (1.f + sc.w) + sh.w;
    ((ushort4*)(out + (size_t)row * 1024))[tid] = make_ushort4(f2bf(h0), f2bf(h1), f2bf(h2), f2bf(h3));
}

// ---------------- MFMA GEMM: C[M,N] = A[M,K] * B[N,K]^T (+epilogue) ----------------
// BM=128: 2x2 waves, 64x64/wave (m97 geometry). BM=64: 1x4 waves, 64x32/wave.
// K-range split across blockIdx.z (gridDim.z=1 -> full K).
// MODE 0: store bf16 | 1: +bias,gelu -> bf16 | 2: f32 out = res + gate*(acc+bias?) | 3: atomic f32 partial
template<int MODE, int BM>
__global__ __launch_bounds__(256) void k_gemm(const unsigned short* __restrict__ A,
                                              const unsigned short* __restrict__ B,
                                              void* __restrict__ outp,
                                              const float* __restrict__ bias,
                                              const float* __restrict__ res,
                                              const float* __restrict__ ada, int goff,
                                              int M, int N, int K){
    constexpr int NT = (BM == 128) ? 4 : 2;
    constexpr int NW = NT * 16;
    __shared__ unsigned short As[BM * 32];
    __shared__ unsigned short Bs[128 * 32];
    int tid = threadIdx.x, lane = tid & 63, wv = tid >> 6;
    int quad = lane >> 4, l15 = lane & 15;
    int wm = (BM == 128) ? (wv & 1) : 0;
    int wn = (BM == 128) ? (wv >> 1) : wv;
    int bm = blockIdx.x, bn = blockIdx.y;
    int kpb = K / gridDim.z;
    int klo = blockIdx.z * kpb, khi = klo + kpb;
    f32x4 acc[4][NT] = {};
    const unsigned short* ga = A + (size_t)(bm * BM + wv * 16 + (lane >> 2)) * K + (lane & 3) * 8;
    const unsigned short* gb = B + (size_t)(bn * 128 + wv * 16 + (lane >> 2)) * K + (lane & 3) * 8;
    size_t stride64 = (size_t)64 * K;
    unsigned short* la0 = As + wv * 16 * 32;
    unsigned short* la1 = As + (wv * 16 + 64) * 32;   // BM==128 only
    unsigned short* lb0 = Bs + wv * 16 * 32;
    unsigned short* lb1 = Bs + (wv * 16 + 64) * 32;
    for (int k0 = klo; k0 < khi; k0 += 32){
        __syncthreads();
        GLDS16(ga + k0, la0);
        if constexpr (BM == 128) GLDS16(ga + stride64 + k0, la1);
        GLDS16(gb + k0, lb0);
        GLDS16(gb + stride64 + k0, lb1);
        __syncthreads();
        bf16x8 af[4], bfr[NT];
        #pragma unroll
        for (int i = 0; i < 4; i++)
            af[i] = *(const bf16x8*)(As + (wm * 64 + i * 16 + l15) * 32 + quad * 8);
        #pragma unroll
        for (int j = 0; j < NT; j++)
            bfr[j] = *(const bf16x8*)(Bs + (wn * NW + j * 16 + l15) * 32 + quad * 8);
        #pragma unroll
        for (int i = 0; i < 4; i++)
            #pragma unroll
            for (int j = 0; j < NT; j++)
                acc[i][j] = __builtin_amdgcn_mfma_f32_16x16x32_bf16(af[i], bfr[j], acc[i][j], 0, 0, 0);
    }
    int row0 = bm * BM + wm * 64, col0 = bn * 128 + wn * NW;
    #pragma unroll
    for (int i = 0; i < 4; i++){
        #pragma unroll
        for (int r = 0; r < 4; r++){
            int row = row0 + i * 16 + quad * 4 + r;
            #pragma unroll
            for (int j = 0; j < NT; j++){
                int col = col0 + j * 16 + l15;
                float v = acc[i][j][r];
                size_t idx = (size_t)row * N + col;
                if constexpr (MODE == 0){
                    ((unsigned short*)outp)[idx] = f2bf(v);
                } else if constexpr (MODE == 1){
                    float t = v + bias[col];
                    float u = 0.7978845608028654f * (t + 0.044715f * t * t * t);
                    float g = 0.5f * t * (1.f + tanhf(u));
                    ((unsigned short*)outp)[idx] = f2bf(g);
                } else if constexpr (MODE == 2){
                    float t = v;
                    if (bias) t += bias[col];
                    int bb = row >> 11;
                    float g = ada[(size_t)bb * 6144 + goff + col];
                    ((float*)outp)[idx] = res[idx] + g * t;
                } else {
                    unsafeAtomicAdd((float*)outp + idx, v);
                }
            }
        }
    }
}

// ---------------- split-K epilogue: out = res + gate*(acc + bias) ----------------
__global__ __launch_bounds__(256) void k_ep(const float* __restrict__ acc,
                                            const float* __restrict__ bias,
                                            const float* __restrict__ res,
                                            const float* __restrict__ ada, int goff,
                                            float* __restrict__ out, int N){
    int row = blockIdx.x;
    int bb  = row >> 11;
    int tid = threadIdx.x;
    const float* adag = ada + (size_t)bb * 6144 + goff;
    size_t base = (size_t)row * N;
    float4 a = ((const float4*)(acc + base))[tid];
    float4 rv = ((const float4*)(res + base))[tid];
    float4 bv = ((const float4*)bias)[tid];
    float4 gv = ((const float4*)adag)[tid];
    float4 o;
    o.x = rv.x + gv.x * (a.x + bv.x);
    o.y = rv.y + gv.y * (a.y + bv.y);
    o.z = rv.z + gv.z * (a.z + bv.z);
    o.w = rv.w + gv.w * (a.w + bv.w);
    ((float4*)(out + base))[tid] = o;
}

// ---------------- V transpose: qkv V-part -> Vt[bh][d][key] ----------------
__global__ __launch_bounds__(256) void k_vt(const unsigned short* __restrict__ qkv,
                                            unsigned short* __restrict__ vt){
    __shared__ unsigned short T[64 * 66];
    int kb = blockIdx.x, bh = blockIdx.y;
    int b = bh >> 4, h = bh & 15;
    size_t rb = (size_t)b * 2048;
    int t = threadIdx.x;
    int key = t >> 2, seg = t & 3;
    const unsigned short* src = qkv + (rb + kb * 64 + key) * 3072 + 2048 + h * 64;
    uint4 v0 = *(const uint4*)(src + seg * 8);
    uint4 v1 = *(const uint4*)(src + 32 + seg * 8);
    const unsigned short* p0 = (const unsigned short*)&v0;
    const unsigned short* p1 = (const unsigned short*)&v1;
    unsigned short* tr = T + key * 66;
    ushort2* t0 = (ushort2*)(tr + seg * 8);
    ushort2* t1 = (ushort2*)(tr + 32 + seg * 8);
    #pragma unroll
    for (int j = 0; j < 4; j++){
        t0[j] = make_ushort2(p0[2*j], p0[2*j+1]);
        t1[j] = make_ushort2(p1[2*j], p1[2*j+1]);
    }
    __syncthreads();
    int d = t >> 2, kseg = t & 3;
    unsigned short obuf[16];
    #pragma unroll
    for (int j = 0; j < 16; j++) obuf[j] = T[(kseg * 16 + j) * 66 + d];
    uint4* dst = (uint4*)(vt + ((size_t)bh * 64 + d) * 2048 + kb * 64 + kseg * 16);
    dst[0] = ((const uint4*)obuf)[0];
    dst[1] = ((const uint4*)obuf)[1];
}

// ---------------- flash attention: B=2,S=2048,H=16,HD=64 ----------------
__global__ __launch_bounds__(256) void k_attn(const unsigned short* __restrict__ qkv,
                                              const unsigned short* __restrict__ vt,
                                              unsigned short* __restrict__ out){
    __shared__ unsigned short Ks[2 * 64 * 32];
    __shared__ unsigned short Vs[2 * 64 * 32];
    __shared__ __align__(16) unsigned short Ps[4 * 32 * 72];
    int tid = threadIdx.x, lane = tid & 63, wv = tid >> 6;
    int quad = lane >> 4, l15 = lane & 15;
    int qt = blockIdx.x, bh = blockIdx.y;
    int b = bh >> 4, h = bh & 15;
    size_t rb = (size_t)b * 2048;

    bf16x8 qb[2][2];
    #pragma unroll
    for (int t = 0; t < 2; t++){
        int qrow = qt * 128 + wv * 32 + t * 16 + l15;
        const unsigned short* qp = qkv + ((rb + qrow) * 3072 + h * 64 + quad * 8);
        qb[t][0] = *(const bf16x8*)qp;
        qb[t][1] = *(const bf16x8*)(qp + 32);
    }
    float lsum[2] = {0.f, 0.f};
    f32x4 o[2][4];
    #pragma unroll
    for (int t = 0; t < 2; t++)
        #pragma unroll
        for (int dt = 0; dt < 4; dt++) o[t][dt] = (f32x4){0.f, 0.f, 0.f, 0.f};

    int rr = wv * 16 + (lane >> 2), cs = lane & 3;
    const unsigned short* gk = qkv + (rb + rr) * 3072 + 1024 + h * 64 + cs * 8;
    const unsigned short* gv = vt + ((size_t)bh * 64 + rr) * 2048 + cs * 8;
    unsigned short* lk0 = Ks + wv * 16 * 32;
    unsigned short* lk1 = Ks + 2048 + wv * 16 * 32;
    unsigned short* lv0 = Vs + wv * 16 * 32;
    unsigned short* lv1 = Vs + 2048 + wv * 16 * 32;
    unsigned short* Pw = Ps + wv * 32 * 72;

    for (int k0 = 0; k0 < 2048; k0 += 64){
        __syncthreads();
        GLDS16(gk + (size_t)k0 * 3072,      lk0);
        GLDS16(gk + (size_t)k0 * 3072 + 32, lk1);
        GLDS16(gv + k0,      lv0);
        GLDS16(gv + k0 + 32, lv1);
        __syncthreads();
        f32x4 c[2][4];
        #pragma unroll
        for (int kt = 0; kt < 4; kt++){
            bf16x8 ka0 = *(const bf16x8*)(Ks + (kt * 16 + l15) * 32 + quad * 8);
            bf16x8 ka1 = *(const bf16x8*)(Ks + 2048 + (kt * 16 + l15) * 32 + quad * 8);
            #pragma unroll
            for (int t = 0; t < 2; t++){
                f32x4 z = (f32x4){0.f, 0.f, 0.f, 0.f};
                z = __builtin_amdgcn_mfma_f32_16x16x32_bf16(ka0, qb[t][0], z, 0, 0, 0);
                z = __builtin_amdgcn_mfma_f32_16x16x32_bf16(ka1, qb[t][1], z, 0, 0, 0);
                c[t][kt] = z;
            }
        }
        #pragma unroll
        for (int t = 0; t < 2; t++){
            #pragma unroll
            for (int kt = 0; kt < 4; kt++){
                float p0 = __expf(c[t][kt][0] * 0.125f);
                float p1 = __expf(c[t][kt][1] * 0.125f);
                float p2 = __expf(c[t][kt][2] * 0.125f);
                float p3 = __expf(c[t][kt][3] * 0.125f);
                lsum[t] += (p0 + p1) + (p2 + p3);
                uint2 w;
                w.x = pk2bf(p0, p1);
                w.y = pk2bf(p2, p3);
                *(uint2*)(Pw + (t * 16 + l15) * 72 + kt * 16 + quad * 4) = w;
            }
        }
        bf16x8 pa[2][2];
        #pragma unroll
        for (int t = 0; t < 2; t++){
            pa[t][0] = *(const bf16x8*)(Pw + (t * 16 + l15) * 72 + quad * 8);
            pa[t][1] = *(const bf16x8*)(Pw + (t * 16 + l15) * 72 + 32 + quad * 8);
        }
        #pragma unroll
        for (int dt = 0; dt < 4; dt++){
            bf16x8 vb0 = *(const bf16x8*)(Vs + (dt * 16 + l15) * 32 + quad * 8);
            bf16x8 vb1 = *(const bf16x8*)(Vs + 2048 + (dt * 16 + l15) * 32 + quad * 8);
            #pragma unroll
            for (int t = 0; t < 2; t++){
                o[t][dt] = __builtin_amdgcn_mfma_f32_16x16x32_bf16(pa[t][0], vb0, o[t][dt], 0, 0, 0);
                o[t][dt] = __builtin_amdgcn_mfma_f32_16x16x32_bf16(pa[t][1], vb1, o[t][dt], 0, 0, 0);
            }
        }
    }
    #pragma unroll
    for (int t = 0; t < 2; t++){
        lsum[t] += __shfl_xor(lsum[t], 16);
        lsum[t] += __shfl_xor(lsum[t], 32);
    }
    #pragma unroll
    for (int t = 0; t < 2; t++){
        #pragma unroll
        for (int r = 0; r < 4; r++){
            float lt = __shfl(lsum[t], quad * 4 + r);
            float inv = 1.f / lt;
            int row = qt * 128 + wv * 32 + t * 16 + quad * 4 + r;
            unsigned short* op = out + ((rb + row) * 1024 + h * 64);
            #pragma unroll
            for (int dt = 0; dt < 4; dt++)
                op[dt * 16 + l15] = f2bf(o[t][dt][r] * inv);
        }
    }
}

extern "C" void kernel_launch(void* const* d_in, const int* in_sizes, int n_in,
                              void* d_out, int out_size, void* d_ws, size_t ws_size,
                              hipStream_t stream){
    const float* x     = (const float*)d_in[0];
    const float* c     = (const float*)d_in[3];
    const float* n1w   = (const float*)d_in[4];
    const float* w_qkv = (const float*)d_in[5];
    const float* w_out = (const float*)d_in[6];
    const float* n2w   = (const float*)d_in[7];
    const float* w1    = (const float*)d_in[8];
    const float* b1    = (const float*)d_in[9];
    const float* w2    = (const float*)d_in[10];
    const float* b2    = (const float*)d_in[11];
    const float* ada_w = (const float*)d_in[12];
    const float* ada_b = (const float*)d_in[13];
    float* out = (float*)d_out;
    char* ws = (char*)d_ws;

    unsigned short* wqkv_b = (unsigned short*)(ws + 0);         //  6 MB
    unsigned short* wout_b = (unsigned short*)(ws + 6291456);   //  2 MB
    unsigned short* w1_b   = (unsigned short*)(ws + 8388608);   //  8 MB
    unsigned short* w2_b   = (unsigned short*)(ws + 16777216);  //  8 MB
    float*          ada    = (float*)         (ws + 25165824);  // 48 KB
    unsigned short* h      = (unsigned short*)(ws + 25214976);  //  8 MB
    unsigned short* qkv    = (unsigned short*)(ws + 33603584);  // 24 MB
    unsigned short* attn   = (unsigned short*)(ws + 58769408);  //  8 MB
    float*          xn     = (float*)         (ws + 67158016);  // 16 MB
    unsigned short* u      = qkv;              // 32 MB, reuses qkv+attn (dead by then)
    unsigned short* vt     = h;                // 8 MB, h dead between qkv-gemm and LN2
    float*          accb   = (float*)ws;       // 16 MB, reuses wqkv_b/wout_b/w1_b (dead by mlp2)

    k_cast_bf16<<<3072, 256, 0, stream>>>(w_qkv, wqkv_b,  786432);
    k_cast_bf16<<<1024, 256, 0, stream>>>(w_out, wout_b,  262144);
    k_cast_bf16<<<4096, 256, 0, stream>>>(w1,    w1_b,   1048576);
    k_cast_bf16<<<4096, 256, 0, stream>>>(w2,    w2_b,   1048576);
    k_ada<<<3072, 256, 0, stream>>>(c, ada_w, ada_b, ada);
    k_ln_mod<<<4096, 256, 0, stream>>>(x, n1w, ada, 0, 1024, h);
    k_gemm<0,128><<<dim3(32, 24), 256, 0, stream>>>(h, wqkv_b, qkv, nullptr, nullptr, nullptr, 0, 4096, 3072, 1024);
    k_vt<<<dim3(32, 32), 256, 0, stream>>>(qkv, vt);
    k_attn<<<dim3(16, 32), 256, 0, stream>>>(qkv, vt, attn);
    k_gemm<2,64><<<dim3(64, 8), 256, 0, stream>>>(attn, wout_b, xn, nullptr, x, ada, 2048, 4096, 1024, 1024);
    k_ln_mod<<<4096, 256, 0, stream>>>(xn, n2w, ada, 3072, 4096, h);
    k_gemm<1,128><<<dim3(32, 32), 256, 0, stream>>>(h, w1_b, u, b1, nullptr, nullptr, 0, 4096, 4096, 1024);
    // mlp2: split-K=4 into f32 atomic accumulator, then epilogue
    hipMemsetAsync(accb, 0, 16777216, stream);
    k_gemm<3,128><<<dim3(32, 8, 4), 256, 0, stream>>>(u, w2_b, accb, nullptr, nullptr, nullptr, 0, 4096, 1024, 4096);
    k_ep<<<4096, 256, 0, stream>>>(accb, b2, xn, ada, 5120, out, 1024);
}

// Round 6
// 438.220 us; speedup vs baseline: 1.0882x; 1.0882x over previous
//
#include <hip/hip_runtime.h>
#include <stdint.h>

typedef __attribute__((ext_vector_type(4))) float f32x4;
typedef __attribute__((ext_vector_type(8))) __bf16 bf16x8;

#define DEV static __device__ __forceinline__

DEV unsigned short f2bf(float f){
    uint32_t u = __float_as_uint(f);
    u += 0x7FFFu + ((u >> 16) & 1u);   // RNE
    return (unsigned short)(u >> 16);
}
DEV uint32_t pk2bf(float a, float b){
    return (uint32_t)f2bf(a) | ((uint32_t)f2bf(b) << 16);
}

// ---------------- f32 -> bf16 cast (weights) ----------------
__global__ __launch_bounds__(256) void k_cast_bf16(const float* __restrict__ in,
                                                   unsigned short* __restrict__ out, int n4){
    int i = blockIdx.x * 256 + threadIdx.x;
    if (i < n4){
        float4 v = ((const float4*)in)[i];
        ((ushort4*)out)[i] = make_ushort4(f2bf(v.x), f2bf(v.y), f2bf(v.z), f2bf(v.w));
    }
}

// ---------------- ada = c @ ada_w^T + ada_b  (2 x 6144) ----------------
__global__ __launch_bounds__(256) void k_ada(const float* __restrict__ c,
                                             const float* __restrict__ aw,
                                             const float* __restrict__ ab,
                                             float* __restrict__ out){
    int wid  = blockIdx.x * 4 + (threadIdx.x >> 6);
    int lane = threadIdx.x & 63;
    int b = wid / 6144, r = wid % 6144;
    const float4* cw = (const float4*)(c + (size_t)b * 1024);
    const float4* wr = (const float4*)(aw + (size_t)r * 1024);
    float s = 0.f;
    #pragma unroll
    for (int i = 0; i < 4; i++){
        float4 a = wr[lane + i * 64];
        float4 q = cw[lane + i * 64];
        s += a.x*q.x + a.y*q.y + a.z*q.z + a.w*q.w;
    }
    #pragma unroll
    for (int off = 32; off > 0; off >>= 1) s += __shfl_down(s, off);
    if (lane == 0) out[wid] = s + ab[r];
}

// ---------------- LN + modulate -> bf16 ----------------
__global__ __launch_bounds__(256) void k_ln_mod(const float* __restrict__ x,
                                                const float* __restrict__ w,
                                                const float* __restrict__ ada,
                                                int sh_off, int sc_off,
                                                unsigned short* __restrict__ out){
    int row = blockIdx.x;
    int b   = row >> 11;
    int tid = threadIdx.x;
    float4 v = ((const float4*)(x + (size_t)row * 1024))[tid];
    float s  = v.x + v.y + v.z + v.w;
    float ss = v.x*v.x + v.y*v.y + v.z*v.z + v.w*v.w;
    #pragma unroll
    for (int off = 32; off > 0; off >>= 1){ s += __shfl_down(s, off); ss += __shfl_down(ss, off); }
    __shared__ float red[8];
    int wv = tid >> 6;
    if ((tid & 63) == 0){ red[wv] = s; red[4 + wv] = ss; }
    __syncthreads();
    float S  = red[0] + red[1] + red[2] + red[3];
    float SS = red[4] + red[5] + red[6] + red[7];
    float mu   = S * (1.f / 1024.f);
    float rstd = rsqrtf(SS * (1.f / 1024.f) - mu * mu + 1e-5f);
    const float* adab = ada + (size_t)b * 6144;
    float4 wv4 = ((const float4*)w)[tid];
    float4 sh  = ((const float4*)(adab + sh_off))[tid];
    float4 sc  = ((const float4*)(adab + sc_off))[tid];
    float h0 = (v.x - mu) * rstd * wv4.x * (1.f + sc.x) + sh.x;
    float h1 = (v.y - mu) * rstd * wv4.y * (1.f + sc.y) + sh.y;
    float h2 = (v.z - mu) * rstd * wv4.z * (1.f + sc.z) + sh.z;
    float h3 = (v.w - mu) * rstd * wv4.w * (1.f + sc.w) + sh.w;
    ((ushort4*)(out + (size_t)row * 1024))[tid] = make_ushort4(f2bf(h0), f2bf(h1), f2bf(h2), f2bf(h3));
}

// ---------------- MFMA GEMM: C[M,N] = A[M,K] * B[N,K]^T (+epilogue) ----------------
// 128x128 tile, 2x2 waves x 64x64 (m97 geometry). Software-pipelined K-loop:
// register prefetch of tile k+1 -> ds_write -> ONE barrier -> ds_read+MFMA,
// double-buffered LDS. vmcnt wait before ds_write covers loads issued a full
// MFMA-block earlier -> global latency hidden even at 1 wave/SIMD.
// MODE 0: store bf16 | 1: +bias,gelu -> bf16 | 2: f32 out = res + gate*(acc+bias?)
template<int MODE>
__global__ __launch_bounds__(256) void k_gemm(const unsigned short* __restrict__ A,
                                              const unsigned short* __restrict__ B,
                                              void* __restrict__ outp,
                                              const float* __restrict__ bias,
                                              const float* __restrict__ res,
                                              const float* __restrict__ ada, int goff,
                                              int M, int N, int K){
    __shared__ unsigned short As[2 * 128 * 32];
    __shared__ unsigned short Bs[2 * 128 * 32];
    int tid = threadIdx.x, lane = tid & 63, wv = tid >> 6;
    int quad = lane >> 4, l15 = lane & 15;
    int wm = wv & 1, wn = wv >> 1;
    int bm = blockIdx.x, bn = blockIdx.y;
    f32x4 acc[4][4] = {};
    int srow = wv * 16 + (lane >> 2), sseg = lane & 3;
    const unsigned short* ga = A + (size_t)(bm * 128 + srow) * K + sseg * 8;
    const unsigned short* gb = B + (size_t)(bn * 128 + srow) * K + sseg * 8;
    size_t stride64 = (size_t)64 * K;
    int soff = srow * 32 + sseg * 8;
    // prefetch tile 0
    uint4 ra0 = *(const uint4*)(ga);
    uint4 ra1 = *(const uint4*)(ga + stride64);
    uint4 rb0 = *(const uint4*)(gb);
    uint4 rb1 = *(const uint4*)(gb + stride64);
    for (int k0 = 0; k0 < K; k0 += 32){
        unsigned short* as = As + ((k0 >> 5) & 1) * 4096;
        unsigned short* bs = Bs + ((k0 >> 5) & 1) * 4096;
        // issue next-tile loads first (fresh regs), then write current tile
        int kn = (k0 + 32 < K) ? (k0 + 32) : k0;
        uint4 na0 = *(const uint4*)(ga + kn);
        uint4 na1 = *(const uint4*)(ga + stride64 + kn);
        uint4 nb0 = *(const uint4*)(gb + kn);
        uint4 nb1 = *(const uint4*)(gb + stride64 + kn);
        *(uint4*)(as + soff)             = ra0;
        *(uint4*)(as + 64 * 32 + soff)   = ra1;
        *(uint4*)(bs + soff)             = rb0;
        *(uint4*)(bs + 64 * 32 + soff)   = rb1;
        __syncthreads();
        ra0 = na0; ra1 = na1; rb0 = nb0; rb1 = nb1;
        bf16x8 af[4], bfr[4];
        #pragma unroll
        for (int i = 0; i < 4; i++)
            af[i] = *(const bf16x8*)(as + (wm * 64 + i * 16 + l15) * 32 + quad * 8);
        #pragma unroll
        for (int j = 0; j < 4; j++)
            bfr[j] = *(const bf16x8*)(bs + (wn * 64 + j * 16 + l15) * 32 + quad * 8);
        #pragma unroll
        for (int i = 0; i < 4; i++)
            #pragma unroll
            for (int j = 0; j < 4; j++)
                acc[i][j] = __builtin_amdgcn_mfma_f32_16x16x32_bf16(af[i], bfr[j], acc[i][j], 0, 0, 0);
    }
    int row0 = bm * 128 + wm * 64, col0 = bn * 128 + wn * 64;
    #pragma unroll
    for (int i = 0; i < 4; i++){
        #pragma unroll
        for (int r = 0; r < 4; r++){
            int row = row0 + i * 16 + quad * 4 + r;
            #pragma unroll
            for (int j = 0; j < 4; j++){
                int col = col0 + j * 16 + l15;
                float v = acc[i][j][r];
                size_t idx = (size_t)row * N + col;
                if constexpr (MODE == 0){
                    ((unsigned short*)outp)[idx] = f2bf(v);
                } else if constexpr (MODE == 1){
                    float t = v + bias[col];
                    float u = 0.7978845608028654f * (t + 0.044715f * t * t * t);
                    float g = 0.5f * t * (1.f + tanhf(u));
                    ((unsigned short*)outp)[idx] = f2bf(g);
                } else {
                    float t = v;
                    if (bias) t += bias[col];
                    int bb = row >> 11;
                    float g = ada[(size_t)bb * 6144 + goff + col];
                    ((float*)outp)[idx] = res[idx] + g * t;
                }
            }
        }
    }
}

// ---------------- V transpose: qkv V-part -> Vt[bh][d][key] ----------------
__global__ __launch_bounds__(256) void k_vt(const unsigned short* __restrict__ qkv,
                                            unsigned short* __restrict__ vt){
    __shared__ unsigned short T[64 * 66];
    int kb = blockIdx.x, bh = blockIdx.y;
    int b = bh >> 4, h = bh & 15;
    size_t rb = (size_t)b * 2048;
    int t = threadIdx.x;
    int key = t >> 2, seg = t & 3;
    const unsigned short* src = qkv + (rb + kb * 64 + key) * 3072 + 2048 + h * 64;
    uint4 v0 = *(const uint4*)(src + seg * 8);
    uint4 v1 = *(const uint4*)(src + 32 + seg * 8);
    const unsigned short* p0 = (const unsigned short*)&v0;
    const unsigned short* p1 = (const unsigned short*)&v1;
    unsigned short* tr = T + key * 66;
    ushort2* t0 = (ushort2*)(tr + seg * 8);
    ushort2* t1 = (ushort2*)(tr + 32 + seg * 8);
    #pragma unroll
    for (int j = 0; j < 4; j++){
        t0[j] = make_ushort2(p0[2*j], p0[2*j+1]);
        t1[j] = make_ushort2(p1[2*j], p1[2*j+1]);
    }
    __syncthreads();
    int d = t >> 2, kseg = t & 3;
    unsigned short obuf[16];
    #pragma unroll
    for (int j = 0; j < 16; j++) obuf[j] = T[(kseg * 16 + j) * 66 + d];
    uint4* dst = (uint4*)(vt + ((size_t)bh * 64 + d) * 2048 + kb * 64 + kseg * 16);
    dst[0] = ((const uint4*)obuf)[0];
    dst[1] = ((const uint4*)obuf)[1];
}

// ---------------- flash attention: B=2,S=2048,H=16,HD=64 ----------------
// Pipelined like k_gemm: K/V register prefetch + double-buffered LDS + 1 barrier/iter.
__global__ __launch_bounds__(256) void k_attn(const unsigned short* __restrict__ qkv,
                                              const unsigned short* __restrict__ vt,
                                              unsigned short* __restrict__ out){
    __shared__ unsigned short Ks[2 * 4096];                  // [buf][d-half][64 keys][32 d]
    __shared__ unsigned short Vs[2 * 4096];                  // [buf][key-half][64 d][32 keys]
    __shared__ __align__(16) unsigned short Ps[4 * 32 * 72]; // per-wave P[32 q][72]
    int tid = threadIdx.x, lane = tid & 63, wv = tid >> 6;
    int quad = lane >> 4, l15 = lane & 15;
    int qt = blockIdx.x, bh = blockIdx.y;
    int b = bh >> 4, h = bh & 15;
    size_t rb = (size_t)b * 2048;

    bf16x8 qb[2][2];
    #pragma unroll
    for (int t = 0; t < 2; t++){
        int qrow = qt * 128 + wv * 32 + t * 16 + l15;
        const unsigned short* qp = qkv + ((rb + qrow) * 3072 + h * 64 + quad * 8);
        qb[t][0] = *(const bf16x8*)qp;
        qb[t][1] = *(const bf16x8*)(qp + 32);
    }
    float lsum[2] = {0.f, 0.f};
    f32x4 o[2][4];
    #pragma unroll
    for (int t = 0; t < 2; t++)
        #pragma unroll
        for (int dt = 0; dt < 4; dt++) o[t][dt] = (f32x4){0.f, 0.f, 0.f, 0.f};

    int rr = wv * 16 + (lane >> 2), cs = lane & 3;
    const unsigned short* gk = qkv + (rb + rr) * 3072 + 1024 + h * 64 + cs * 8;
    const unsigned short* gv = vt + ((size_t)bh * 64 + rr) * 2048 + cs * 8;
    int soff = rr * 32 + cs * 8;
    unsigned short* Pw = Ps + wv * 32 * 72;

    // prefetch tile 0
    uint4 rk0 = *(const uint4*)(gk);
    uint4 rk1 = *(const uint4*)(gk + 32);
    uint4 rv0 = *(const uint4*)(gv);
    uint4 rv1 = *(const uint4*)(gv + 32);

    for (int k0 = 0; k0 < 2048; k0 += 64){
        unsigned short* ks = Ks + ((k0 >> 6) & 1) * 4096;
        unsigned short* vs = Vs + ((k0 >> 6) & 1) * 4096;
        int kn = (k0 + 64 < 2048) ? (k0 + 64) : k0;
        uint4 nk0 = *(const uint4*)(gk + (size_t)kn * 3072);
        uint4 nk1 = *(const uint4*)(gk + (size_t)kn * 3072 + 32);
        uint4 nv0 = *(const uint4*)(gv + kn);
        uint4 nv1 = *(const uint4*)(gv + kn + 32);
        *(uint4*)(ks + soff)        = rk0;
        *(uint4*)(ks + 2048 + soff) = rk1;
        *(uint4*)(vs + soff)        = rv0;
        *(uint4*)(vs + 2048 + soff) = rv1;
        __syncthreads();
        rk0 = nk0; rk1 = nk1; rv0 = nv0; rv1 = nv1;
        f32x4 c[2][4];
        #pragma unroll
        for (int kt = 0; kt < 4; kt++){
            bf16x8 ka0 = *(const bf16x8*)(ks + (kt * 16 + l15) * 32 + quad * 8);
            bf16x8 ka1 = *(const bf16x8*)(ks + 2048 + (kt * 16 + l15) * 32 + quad * 8);
            #pragma unroll
            for (int t = 0; t < 2; t++){
                f32x4 z = (f32x4){0.f, 0.f, 0.f, 0.f};
                z = __builtin_amdgcn_mfma_f32_16x16x32_bf16(ka0, qb[t][0], z, 0, 0, 0);
                z = __builtin_amdgcn_mfma_f32_16x16x32_bf16(ka1, qb[t][1], z, 0, 0, 0);
                c[t][kt] = z;
            }
        }
        #pragma unroll
        for (int t = 0; t < 2; t++){
            #pragma unroll
            for (int kt = 0; kt < 4; kt++){
                float p0 = __expf(c[t][kt][0] * 0.125f);
                float p1 = __expf(c[t][kt][1] * 0.125f);
                float p2 = __expf(c[t][kt][2] * 0.125f);
                float p3 = __expf(c[t][kt][3] * 0.125f);
                lsum[t] += (p0 + p1) + (p2 + p3);
                uint2 w;
                w.x = pk2bf(p0, p1);
                w.y = pk2bf(p2, p3);
                *(uint2*)(Pw + (t * 16 + l15) * 72 + kt * 16 + quad * 4) = w;
            }
        }
        bf16x8 pa[2][2];
        #pragma unroll
        for (int t = 0; t < 2; t++){
            pa[t][0] = *(const bf16x8*)(Pw + (t * 16 + l15) * 72 + quad * 8);
            pa[t][1] = *(const bf16x8*)(Pw + (t * 16 + l15) * 72 + 32 + quad * 8);
        }
        #pragma unroll
        for (int dt = 0; dt < 4; dt++){
            bf16x8 vb0 = *(const bf16x8*)(vs + (dt * 16 + l15) * 32 + quad * 8);
            bf16x8 vb1 = *(const bf16x8*)(vs + 2048 + (dt * 16 + l15) * 32 + quad * 8);
            #pragma unroll
            for (int t = 0; t < 2; t++){
                o[t][dt] = __builtin_amdgcn_mfma_f32_16x16x32_bf16(pa[t][0], vb0, o[t][dt], 0, 0, 0);
                o[t][dt] = __builtin_amdgcn_mfma_f32_16x16x32_bf16(pa[t][1], vb1, o[t][dt], 0, 0, 0);
            }
        }
    }
    #pragma unroll
    for (int t = 0; t < 2; t++){
        lsum[t] += __shfl_xor(lsum[t], 16);
        lsum[t] += __shfl_xor(lsum[t], 32);
    }
    #pragma unroll
    for (int t = 0; t < 2; t++){
        #pragma unroll
        for (int r = 0; r < 4; r++){
            float lt = __shfl(lsum[t], quad * 4 + r);
            float inv = 1.f / lt;
            int row = qt * 128 + wv * 32 + t * 16 + quad * 4 + r;
            unsigned short* op = out + ((rb + row) * 1024 + h * 64);
            #pragma unroll
            for (int dt = 0; dt < 4; dt++)
                op[dt * 16 + l15] = f2bf(o[t][dt][r] * inv);
        }
    }
}

extern "C" void kernel_launch(void* const* d_in, const int* in_sizes, int n_in,
                              void* d_out, int out_size, void* d_ws, size_t ws_size,
                              hipStream_t stream){
    const float* x     = (const float*)d_in[0];
    const float* c     = (const float*)d_in[3];
    const float* n1w   = (const float*)d_in[4];
    const float* w_qkv = (const float*)d_in[5];
    const float* w_out = (const float*)d_in[6];
    const float* n2w   = (const float*)d_in[7];
    const float* w1    = (const float*)d_in[8];
    const float* b1    = (const float*)d_in[9];
    const float* w2    = (const float*)d_in[10];
    const float* b2    = (const float*)d_in[11];
    const float* ada_w = (const float*)d_in[12];
    const float* ada_b = (const float*)d_in[13];
    float* out = (float*)d_out;
    char* ws = (char*)d_ws;

    unsigned short* wqkv_b = (unsigned short*)(ws + 0);         //  6 MB
    unsigned short* wout_b = (unsigned short*)(ws + 6291456);   //  2 MB
    unsigned short* w1_b   = (unsigned short*)(ws + 8388608);   //  8 MB
    unsigned short* w2_b   = (unsigned short*)(ws + 16777216);  //  8 MB
    float*          ada    = (float*)         (ws + 25165824);  // 48 KB
    unsigned short* h      = (unsigned short*)(ws + 25214976);  //  8 MB
    unsigned short* qkv    = (unsigned short*)(ws + 33603584);  // 24 MB
    unsigned short* attn   = (unsigned short*)(ws + 58769408);  //  8 MB
    float*          xn     = (float*)         (ws + 67158016);  // 16 MB
    unsigned short* u      = qkv;              // 32 MB, reuses qkv+attn (dead by then)
    unsigned short* vt     = h;                // 8 MB, h dead between qkv-gemm and LN2

    k_cast_bf16<<<3072, 256, 0, stream>>>(w_qkv, wqkv_b,  786432);
    k_cast_bf16<<<1024, 256, 0, stream>>>(w_out, wout_b,  262144);
    k_cast_bf16<<<4096, 256, 0, stream>>>(w1,    w1_b,   1048576);
    k_cast_bf16<<<4096, 256, 0, stream>>>(w2,    w2_b,   1048576);
    k_ada<<<3072, 256, 0, stream>>>(c, ada_w, ada_b, ada);
    k_ln_mod<<<4096, 256, 0, stream>>>(x, n1w, ada, 0, 1024, h);
    k_gemm<0><<<dim3(32, 24), 256, 0, stream>>>(h, wqkv_b, qkv, nullptr, nullptr, nullptr, 0, 4096, 3072, 1024);
    k_vt<<<dim3(32, 32), 256, 0, stream>>>(qkv, vt);
    k_attn<<<dim3(16, 32), 256, 0, stream>>>(qkv, vt, attn);
    k_gemm<2><<<dim3(32, 8), 256, 0, stream>>>(attn, wout_b, xn, nullptr, x, ada, 2048, 4096, 1024, 1024);
    k_ln_mod<<<4096, 256, 0, stream>>>(xn, n2w, ada, 3072, 4096, h);
    k_gemm<1><<<dim3(32, 32), 256, 0, stream>>>(h, w1_b, u, b1, nullptr, nullptr, 0, 4096, 4096, 1024);
    k_gemm<2><<<dim3(32, 8), 256, 0, stream>>>(u, w2_b, out, b2, xn, ada, 5120, 4096, 1024, 4096);
}

// Round 7
// 425.987 us; speedup vs baseline: 1.1195x; 1.0287x over previous
//
#include <hip/hip_runtime.h>
#include <stdint.h>

typedef __attribute__((ext_vector_type(4))) float f32x4;
typedef __attribute__((ext_vector_type(8))) __bf16 bf16x8;

#define DEV static __device__ __forceinline__

DEV unsigned short f2bf(float f){
    uint32_t u = __float_as_uint(f);
    u += 0x7FFFu + ((u >> 16) & 1u);   // RNE
    return (unsigned short)(u >> 16);
}
DEV float bf2f(unsigned short s){
    uint32_t u = ((uint32_t)s) << 16;
    return __uint_as_float(u);
}
DEV uint32_t pk2bf(float a, float b){
    return (uint32_t)f2bf(a) | ((uint32_t)f2bf(b) << 16);
}

// ---------------- f32 -> bf16 cast (weights) ----------------
__global__ __launch_bounds__(256) void k_cast_bf16(const float* __restrict__ in,
                                                   unsigned short* __restrict__ out, int n4){
    int i = blockIdx.x * 256 + threadIdx.x;
    if (i < n4){
        float4 v = ((const float4*)in)[i];
        ((ushort4*)out)[i] = make_ushort4(f2bf(v.x), f2bf(v.y), f2bf(v.z), f2bf(v.w));
    }
}

// ---------------- ada = c @ ada_w^T + ada_b  (2 x 6144) ----------------
__global__ __launch_bounds__(256) void k_ada(const float* __restrict__ c,
                                             const float* __restrict__ aw,
                                             const float* __restrict__ ab,
                                             float* __restrict__ out){
    int wid  = blockIdx.x * 4 + (threadIdx.x >> 6);
    int lane = threadIdx.x & 63;
    int b = wid / 6144, r = wid % 6144;
    const float4* cw = (const float4*)(c + (size_t)b * 1024);
    const float4* wr = (const float4*)(aw + (size_t)r * 1024);
    float s = 0.f;
    #pragma unroll
    for (int i = 0; i < 4; i++){
        float4 a = wr[lane + i * 64];
        float4 q = cw[lane + i * 64];
        s += a.x*q.x + a.y*q.y + a.z*q.z + a.w*q.w;
    }
    #pragma unroll
    for (int off = 32; off > 0; off >>= 1) s += __shfl_down(s, off);
    if (lane == 0) out[wid] = s + ab[r];
}

// ---------------- LN + modulate -> bf16 ----------------
__global__ __launch_bounds__(256) void k_ln_mod(const float* __restrict__ x,
                                                const float* __restrict__ w,
                                                const float* __restrict__ ada,
                                                int sh_off, int sc_off,
                                                unsigned short* __restrict__ out){
    int row = blockIdx.x;
    int b   = row >> 11;
    int tid = threadIdx.x;
    float4 v = ((const float4*)(x + (size_t)row * 1024))[tid];
    float s  = v.x + v.y + v.z + v.w;
    float ss = v.x*v.x + v.y*v.y + v.z*v.z + v.w*v.w;
    #pragma unroll
    for (int off = 32; off > 0; off >>= 1){ s += __shfl_down(s, off); ss += __shfl_down(ss, off); }
    __shared__ float red[8];
    int wv = tid >> 6;
    if ((tid & 63) == 0){ red[wv] = s; red[4 + wv] = ss; }
    __syncthreads();
    float S  = red[0] + red[1] + red[2] + red[3];
    float SS = red[4] + red[5] + red[6] + red[7];
    float mu   = S * (1.f / 1024.f);
    float rstd = rsqrtf(SS * (1.f / 1024.f) - mu * mu + 1e-5f);
    const float* adab = ada + (size_t)b * 6144;
    float4 wv4 = ((const float4*)w)[tid];
    float4 sh  = ((const float4*)(adab + sh_off))[tid];
    float4 sc  = ((const float4*)(adab + sc_off))[tid];
    float h0 = (v.x - mu) * rstd * wv4.x * (1.f + sc.x) + sh.x;
    float h1 = (v.y - mu) * rstd * wv4.y * (1.f + sc.y) + sh.y;
    float h2 = (v.z - mu) * rstd * wv4.z * (1.f + sc.z) + sh.z;
    float h3 = (v.w - mu) * rstd * wv4.w * (1.f + sc.w) + sh.w;
    ((ushort4*)(out + (size_t)row * 1024))[tid] = make_ushort4(f2bf(h0), f2bf(h1), f2bf(h2), f2bf(h3));
}

// ---------------- MFMA GEMM: C[M,N] = A[M,K] * B[N,K]^T (+epilogue) ----------------
// 128x128 tile, 2x2 waves x 64x64 (m97 geometry). Software-pipelined K-loop:
// register prefetch of tile k+1 -> ds_write -> ONE barrier -> ds_read+MFMA,
// double-buffered LDS. K-range split across blockIdx.z.
// MODE 0: store bf16 | 1: +bias,gelu -> bf16 | 2: f32 out = res + gate*(acc+bias?)
// MODE 3: split-K bf16 partial. outp = z01 (2 contiguous 8MB bufs); bias/res carry z2/z3.
template<int MODE>
__global__ __launch_bounds__(256) void k_gemm(const unsigned short* __restrict__ A,
                                              const unsigned short* __restrict__ B,
                                              void* __restrict__ outp,
                                              const float* __restrict__ bias,
                                              const float* __restrict__ res,
                                              const float* __restrict__ ada, int goff,
                                              int M, int N, int K){
    __shared__ unsigned short As[2 * 128 * 32];
    __shared__ unsigned short Bs[2 * 128 * 32];
    int tid = threadIdx.x, lane = tid & 63, wv = tid >> 6;
    int quad = lane >> 4, l15 = lane & 15;
    int wm = wv & 1, wn = wv >> 1;
    int bm = blockIdx.x, bn = blockIdx.y;
    int kpb = K / gridDim.z;
    int klo = blockIdx.z * kpb, khi = klo + kpb;
    f32x4 acc[4][4] = {};
    int srow = wv * 16 + (lane >> 2), sseg = lane & 3;
    const unsigned short* ga = A + (size_t)(bm * 128 + srow) * K + sseg * 8;
    const unsigned short* gb = B + (size_t)(bn * 128 + srow) * K + sseg * 8;
    size_t stride64 = (size_t)64 * K;
    int soff = srow * 32 + sseg * 8;
    // prefetch first tile
    uint4 ra0 = *(const uint4*)(ga + klo);
    uint4 ra1 = *(const uint4*)(ga + stride64 + klo);
    uint4 rb0 = *(const uint4*)(gb + klo);
    uint4 rb1 = *(const uint4*)(gb + stride64 + klo);
    for (int k0 = klo; k0 < khi; k0 += 32){
        unsigned short* as = As + ((k0 >> 5) & 1) * 4096;
        unsigned short* bs = Bs + ((k0 >> 5) & 1) * 4096;
        int kn = (k0 + 32 < khi) ? (k0 + 32) : k0;
        uint4 na0 = *(const uint4*)(ga + kn);
        uint4 na1 = *(const uint4*)(ga + stride64 + kn);
        uint4 nb0 = *(const uint4*)(gb + kn);
        uint4 nb1 = *(const uint4*)(gb + stride64 + kn);
        *(uint4*)(as + soff)             = ra0;
        *(uint4*)(as + 64 * 32 + soff)   = ra1;
        *(uint4*)(bs + soff)             = rb0;
        *(uint4*)(bs + 64 * 32 + soff)   = rb1;
        __syncthreads();
        ra0 = na0; ra1 = na1; rb0 = nb0; rb1 = nb1;
        bf16x8 af[4], bfr[4];
        #pragma unroll
        for (int i = 0; i < 4; i++)
            af[i] = *(const bf16x8*)(as + (wm * 64 + i * 16 + l15) * 32 + quad * 8);
        #pragma unroll
        for (int j = 0; j < 4; j++)
            bfr[j] = *(const bf16x8*)(bs + (wn * 64 + j * 16 + l15) * 32 + quad * 8);
        #pragma unroll
        for (int i = 0; i < 4; i++)
            #pragma unroll
            for (int j = 0; j < 4; j++)
                acc[i][j] = __builtin_amdgcn_mfma_f32_16x16x32_bf16(af[i], bfr[j], acc[i][j], 0, 0, 0);
    }
    unsigned short* zp = nullptr;
    if constexpr (MODE == 3){
        int z = blockIdx.z;
        if (z < 2)       zp = (unsigned short*)outp + (size_t)z * 4194304;
        else if (z == 2) zp = (unsigned short*)(void*)bias;
        else             zp = (unsigned short*)(void*)res;
    }
    int row0 = bm * 128 + wm * 64, col0 = bn * 128 + wn * 64;
    #pragma unroll
    for (int i = 0; i < 4; i++){
        #pragma unroll
        for (int r = 0; r < 4; r++){
            int row = row0 + i * 16 + quad * 4 + r;
            #pragma unroll
            for (int j = 0; j < 4; j++){
                int col = col0 + j * 16 + l15;
                float v = acc[i][j][r];
                size_t idx = (size_t)row * N + col;
                if constexpr (MODE == 0){
                    ((unsigned short*)outp)[idx] = f2bf(v);
                } else if constexpr (MODE == 1){
                    float t = v + bias[col];
                    float u = 0.7978845608028654f * (t + 0.044715f * t * t * t);
                    float g = 0.5f * t * (1.f + tanhf(u));
                    ((unsigned short*)outp)[idx] = f2bf(g);
                } else if constexpr (MODE == 2){
                    float t = v;
                    if (bias) t += bias[col];
                    int bb = row >> 11;
                    float g = ada[(size_t)bb * 6144 + goff + col];
                    ((float*)outp)[idx] = res[idx] + g * t;
                } else {
                    zp[idx] = f2bf(v);
                }
            }
        }
    }
}

// ---------------- split-K epilogue: out = res + gate*(sum of 4 bf16 partials + bias) ----------------
__global__ __launch_bounds__(256) void k_ep2(const unsigned short* __restrict__ z01,
                                             const unsigned short* __restrict__ z2,
                                             const unsigned short* __restrict__ z3,
                                             const float* __restrict__ bias,
                                             const float* __restrict__ res,
                                             const float* __restrict__ ada, int goff,
                                             float* __restrict__ out){
    int row = blockIdx.x;
    int bb  = row >> 11;
    int tid = threadIdx.x;
    size_t base = (size_t)row * 1024 + tid * 4;
    ushort4 a0 = *(const ushort4*)(z01 + base);
    ushort4 a1 = *(const ushort4*)(z01 + 4194304 + base);
    ushort4 a2 = *(const ushort4*)(z2 + base);
    ushort4 a3 = *(const ushort4*)(z3 + base);
    float4 rv = *(const float4*)(res + base);
    float4 bv = ((const float4*)bias)[tid];
    float4 gv = ((const float4*)(ada + (size_t)bb * 6144 + goff))[tid];
    float4 o;
    o.x = rv.x + gv.x * (bf2f(a0.x) + bf2f(a1.x) + bf2f(a2.x) + bf2f(a3.x) + bv.x);
    o.y = rv.y + gv.y * (bf2f(a0.y) + bf2f(a1.y) + bf2f(a2.y) + bf2f(a3.y) + bv.y);
    o.z = rv.z + gv.z * (bf2f(a0.z) + bf2f(a1.z) + bf2f(a2.z) + bf2f(a3.z) + bv.z);
    o.w = rv.w + gv.w * (bf2f(a0.w) + bf2f(a1.w) + bf2f(a2.w) + bf2f(a3.w) + bv.w);
    *(float4*)(out + base) = o;
}

// ---------------- V transpose: qkv V-part -> Vt[bh][d][key] ----------------
__global__ __launch_bounds__(256) void k_vt(const unsigned short* __restrict__ qkv,
                                            unsigned short* __restrict__ vt){
    __shared__ unsigned short T[64 * 66];
    int kb = blockIdx.x, bh = blockIdx.y;
    int b = bh >> 4, h = bh & 15;
    size_t rb = (size_t)b * 2048;
    int t = threadIdx.x;
    int key = t >> 2, seg = t & 3;
    const unsigned short* src = qkv + (rb + kb * 64 + key) * 3072 + 2048 + h * 64;
    uint4 v0 = *(const uint4*)(src + seg * 8);
    uint4 v1 = *(const uint4*)(src + 32 + seg * 8);
    const unsigned short* p0 = (const unsigned short*)&v0;
    const unsigned short* p1 = (const unsigned short*)&v1;
    unsigned short* tr = T + key * 66;
    ushort2* t0 = (ushort2*)(tr + seg * 8);
    ushort2* t1 = (ushort2*)(tr + 32 + seg * 8);
    #pragma unroll
    for (int j = 0; j < 4; j++){
        t0[j] = make_ushort2(p0[2*j], p0[2*j+1]);
        t1[j] = make_ushort2(p1[2*j], p1[2*j+1]);
    }
    __syncthreads();
    int d = t >> 2, kseg = t & 3;
    unsigned short obuf[16];
    #pragma unroll
    for (int j = 0; j < 16; j++) obuf[j] = T[(kseg * 16 + j) * 66 + d];
    uint4* dst = (uint4*)(vt + ((size_t)bh * 64 + d) * 2048 + kb * 64 + kseg * 16);
    dst[0] = ((const uint4*)obuf)[0];
    dst[1] = ((const uint4*)obuf)[1];
}

// ---------------- flash attention: B=2,S=2048,H=16,HD=64 ----------------
__global__ __launch_bounds__(256) void k_attn(const unsigned short* __restrict__ qkv,
                                              const unsigned short* __restrict__ vt,
                                              unsigned short* __restrict__ out){
    __shared__ unsigned short Ks[2 * 4096];
    __shared__ unsigned short Vs[2 * 4096];
    __shared__ __align__(16) unsigned short Ps[4 * 32 * 72];
    int tid = threadIdx.x, lane = tid & 63, wv = tid >> 6;
    int quad = lane >> 4, l15 = lane & 15;
    int qt = blockIdx.x, bh = blockIdx.y;
    int b = bh >> 4, h = bh & 15;
    size_t rb = (size_t)b * 2048;

    bf16x8 qb[2][2];
    #pragma unroll
    for (int t = 0; t < 2; t++){
        int qrow = qt * 128 + wv * 32 + t * 16 + l15;
        const unsigned short* qp = qkv + ((rb + qrow) * 3072 + h * 64 + quad * 8);
        qb[t][0] = *(const bf16x8*)qp;
        qb[t][1] = *(const bf16x8*)(qp + 32);
    }
    float lsum[2] = {0.f, 0.f};
    f32x4 o[2][4];
    #pragma unroll
    for (int t = 0; t < 2; t++)
        #pragma unroll
        for (int dt = 0; dt < 4; dt++) o[t][dt] = (f32x4){0.f, 0.f, 0.f, 0.f};

    int rr = wv * 16 + (lane >> 2), cs = lane & 3;
    const unsigned short* gk = qkv + (rb + rr) * 3072 + 1024 + h * 64 + cs * 8;
    const unsigned short* gv = vt + ((size_t)bh * 64 + rr) * 2048 + cs * 8;
    int soff = rr * 32 + cs * 8;
    unsigned short* Pw = Ps + wv * 32 * 72;

    uint4 rk0 = *(const uint4*)(gk);
    uint4 rk1 = *(const uint4*)(gk + 32);
    uint4 rv0 = *(const uint4*)(gv);
    uint4 rv1 = *(const uint4*)(gv + 32);

    for (int k0 = 0; k0 < 2048; k0 += 64){
        unsigned short* ks = Ks + ((k0 >> 6) & 1) * 4096;
        unsigned short* vs = Vs + ((k0 >> 6) & 1) * 4096;
        int kn = (k0 + 64 < 2048) ? (k0 + 64) : k0;
        uint4 nk0 = *(const uint4*)(gk + (size_t)kn * 3072);
        uint4 nk1 = *(const uint4*)(gk + (size_t)kn * 3072 + 32);
        uint4 nv0 = *(const uint4*)(gv + kn);
        uint4 nv1 = *(const uint4*)(gv + kn + 32);
        *(uint4*)(ks + soff)        = rk0;
        *(uint4*)(ks + 2048 + soff) = rk1;
        *(uint4*)(vs + soff)        = rv0;
        *(uint4*)(vs + 2048 + soff) = rv1;
        __syncthreads();
        rk0 = nk0; rk1 = nk1; rv0 = nv0; rv1 = nv1;
        f32x4 c[2][4];
        #pragma unroll
        for (int kt = 0; kt < 4; kt++){
            bf16x8 ka0 = *(const bf16x8*)(ks + (kt * 16 + l15) * 32 + quad * 8);
            bf16x8 ka1 = *(const bf16x8*)(ks + 2048 + (kt * 16 + l15) * 32 + quad * 8);
            #pragma unroll
            for (int t = 0; t < 2; t++){
                f32x4 z = (f32x4){0.f, 0.f, 0.f, 0.f};
                z = __builtin_amdgcn_mfma_f32_16x16x32_bf16(ka0, qb[t][0], z, 0, 0, 0);
                z = __builtin_amdgcn_mfma_f32_16x16x32_bf16(ka1, qb[t][1], z, 0, 0, 0);
                c[t][kt] = z;
            }
        }
        #pragma unroll
        for (int t = 0; t < 2; t++){
            #pragma unroll
            for (int kt = 0; kt < 4; kt++){
                float p0 = __expf(c[t][kt][0] * 0.125f);
                float p1 = __expf(c[t][kt][1] * 0.125f);
                float p2 = __expf(c[t][kt][2] * 0.125f);
                float p3 = __expf(c[t][kt][3] * 0.125f);
                lsum[t] += (p0 + p1) + (p2 + p3);
                uint2 w;
                w.x = pk2bf(p0, p1);
                w.y = pk2bf(p2, p3);
                *(uint2*)(Pw + (t * 16 + l15) * 72 + kt * 16 + quad * 4) = w;
            }
        }
        bf16x8 pa[2][2];
        #pragma unroll
        for (int t = 0; t < 2; t++){
            pa[t][0] = *(const bf16x8*)(Pw + (t * 16 + l15) * 72 + quad * 8);
            pa[t][1] = *(const bf16x8*)(Pw + (t * 16 + l15) * 72 + 32 + quad * 8);
        }
        #pragma unroll
        for (int dt = 0; dt < 4; dt++){
            bf16x8 vb0 = *(const bf16x8*)(vs + (dt * 16 + l15) * 32 + quad * 8);
            bf16x8 vb1 = *(const bf16x8*)(vs + 2048 + (dt * 16 + l15) * 32 + quad * 8);
            #pragma unroll
            for (int t = 0; t < 2; t++){
                o[t][dt] = __builtin_amdgcn_mfma_f32_16x16x32_bf16(pa[t][0], vb0, o[t][dt], 0, 0, 0);
                o[t][dt] = __builtin_amdgcn_mfma_f32_16x16x32_bf16(pa[t][1], vb1, o[t][dt], 0, 0, 0);
            }
        }
    }
    #pragma unroll
    for (int t = 0; t < 2; t++){
        lsum[t] += __shfl_xor(lsum[t], 16);
        lsum[t] += __shfl_xor(lsum[t], 32);
    }
    #pragma unroll
    for (int t = 0; t < 2; t++){
        #pragma unroll
        for (int r = 0; r < 4; r++){
            float lt = __shfl(lsum[t], quad * 4 + r);
            float inv = 1.f / lt;
            int row = qt * 128 + wv * 32 + t * 16 + quad * 4 + r;
            unsigned short* op = out + ((rb + row) * 1024 + h * 64);
            #pragma unroll
            for (int dt = 0; dt < 4; dt++)
                op[dt * 16 + l15] = f2bf(o[t][dt][r] * inv);
        }
    }
}

extern "C" void kernel_launch(void* const* d_in, const int* in_sizes, int n_in,
                              void* d_out, int out_size, void* d_ws, size_t ws_size,
                              hipStream_t stream){
    const float* x     = (const float*)d_in[0];
    const float* c     = (const float*)d_in[3];
    const float* n1w   = (const float*)d_in[4];
    const float* w_qkv = (const float*)d_in[5];
    const float* w_out = (const float*)d_in[6];
    const float* n2w   = (const float*)d_in[7];
    const float* w1    = (const float*)d_in[8];
    const float* b1    = (const float*)d_in[9];
    const float* w2    = (const float*)d_in[10];
    const float* b2    = (const float*)d_in[11];
    const float* ada_w = (const float*)d_in[12];
    const float* ada_b = (const float*)d_in[13];
    float* out = (float*)d_out;
    char* ws = (char*)d_ws;

    unsigned short* wqkv_b = (unsigned short*)(ws + 0);         //  6 MB
    unsigned short* wout_b = (unsigned short*)(ws + 6291456);   //  2 MB
    unsigned short* w1_b   = (unsigned short*)(ws + 8388608);   //  8 MB
    unsigned short* w2_b   = (unsigned short*)(ws + 16777216);  //  8 MB
    float*          ada    = (float*)         (ws + 25165824);  // 48 KB
    unsigned short* h      = (unsigned short*)(ws + 25214976);  //  8 MB
    unsigned short* qkv    = (unsigned short*)(ws + 33603584);  // 24 MB
    unsigned short* attn   = (unsigned short*)(ws + 58769408);  //  8 MB
    float*          xn     = (float*)         (ws + 67158016);  // 16 MB
    unsigned short* u      = qkv;              // 32 MB, reuses qkv+attn (dead by then)
    unsigned short* vt     = h;                // 8 MB, h dead between qkv-gemm and LN2
    // split-K partial buffers for mlp2 (all regions dead by then):
    unsigned short* z01 = (unsigned short*)(ws + 0);         // 16 MB (wqkv_b+wout_b, z=0,1)
    unsigned short* z2  = (unsigned short*)(ws + 25214976);  //  8 MB (h region)
    unsigned short* z3  = (unsigned short*)(ws + 58769408);  //  8 MB (attn region)

    k_cast_bf16<<<3072, 256, 0, stream>>>(w_qkv, wqkv_b,  786432);
    k_cast_bf16<<<1024, 256, 0, stream>>>(w_out, wout_b,  262144);
    k_cast_bf16<<<4096, 256, 0, stream>>>(w1,    w1_b,   1048576);
    k_cast_bf16<<<4096, 256, 0, stream>>>(w2,    w2_b,   1048576);
    k_ada<<<3072, 256, 0, stream>>>(c, ada_w, ada_b, ada);
    k_ln_mod<<<4096, 256, 0, stream>>>(x, n1w, ada, 0, 1024, h);
    k_gemm<0><<<dim3(32, 24), 256, 0, stream>>>(h, wqkv_b, qkv, nullptr, nullptr, nullptr, 0, 4096, 3072, 1024);
    k_vt<<<dim3(32, 32), 256, 0, stream>>>(qkv, vt);
    k_attn<<<dim3(16, 32), 256, 0, stream>>>(qkv, vt, attn);
    k_gemm<2><<<dim3(32, 8), 256, 0, stream>>>(attn, wout_b, xn, nullptr, x, ada, 2048, 4096, 1024, 1024);
    k_ln_mod<<<4096, 256, 0, stream>>>(xn, n2w, ada, 3072, 4096, h);
    k_gemm<1><<<dim3(32, 32), 256, 0, stream>>>(h, w1_b, u, b1, nullptr, nullptr, 0, 4096, 4096, 1024);
    // mlp2: split-K=4 into 4 private bf16 partial tiles (no atomics), then summing epilogue
    k_gemm<3><<<dim3(32, 8, 4), 256, 0, stream>>>(u, w2_b, z01, (const float*)z2, (const float*)z3,
                                                  nullptr, 0, 4096, 1024, 4096);
    k_ep2<<<4096, 256, 0, stream>>>(z01, z2, z3, b2, xn, ada, 5120, out);
}